// Round 1
// 1424.885 us; speedup vs baseline: 1.3152x; 1.3152x over previous
//
#include <hip/hip_runtime.h>
#include <hip/hip_bf16.h>

// ---------------------------------------------------------------------------
// RNN_20572893348005: 2-layer tanh RNN, B=64 T=1024 D=128 H=256, out [B,H,T]
//
// v2: fused two-layer scan. Per chunk c:
//   proj0 (K=128): xw0 = x_chunk @ W_ih0^T + b0            (parallel GEMM)
//   fused_scan   : 768 thr/WG, 1 WG/batch, 3 groups:
//       G0 : h0[t]  = tanh(xw0[t] + W_hh0 h0[t-1])
//       G1a: xw1[t] = b1 + W_ih1 h0[t]          (lag 1 behind G0)
//       G1b: h1[t]  = tanh(xw1[t] + W_hh1 h1[t-1])  (lag 2), out stored late
//   transpose    : tmp [b][tc][j] f16 -> out [b][j][t] (bf16|f32)
// Eliminates proj1, the h0 global round-trip, and the strided LAST-scan
// writes; halves sequential step count (T instead of 2T).
// Weight rows pinned in VGPRs via empty asm (VGPR_Count=80 showed demotion).
// ---------------------------------------------------------------------------

#define B_ 64
#define T_ 1024
#define D_ 128
#define H_ 256

typedef _Float16 half2_t __attribute__((ext_vector_type(2)));

__device__ __forceinline__ float bf2f(unsigned short u) {
    union { unsigned int i; float f; } v;
    v.i = ((unsigned int)u) << 16;
    return v.f;
}

__device__ __forceinline__ unsigned int cvt2_bf16_to_f16(unsigned int u) {
    union { float f; unsigned int i; } a, b;
    a.i = u << 16;
    b.i = u & 0xFFFF0000u;
    union { _Float16 h[2]; unsigned int u; } r;
    r.h[0] = (_Float16)a.f;
    r.h[1] = (_Float16)b.f;
    return r.u;
}

__device__ __forceinline__ uint4 cvt8_bf16_to_f16(uint4 v) {
    uint4 r;
    r.x = cvt2_bf16_to_f16(v.x);
    r.y = cvt2_bf16_to_f16(v.y);
    r.z = cvt2_bf16_to_f16(v.z);
    r.w = cvt2_bf16_to_f16(v.w);
    return r;
}

__device__ __forceinline__ float dot2(unsigned int a, unsigned int b, float c) {
    union { unsigned int u; half2_t h; } ua, ub;
    ua.u = a; ub.u = b;
#if defined(__HIP_DEVICE_COMPILE__) && __has_builtin(__builtin_amdgcn_fdot2)
    return __builtin_amdgcn_fdot2(ua.h, ub.h, c, false);
#else
    return c + (float)ua.h.x * (float)ub.h.x + (float)ua.h.y * (float)ub.h.y;
#endif
}

// branch-free tanh: (e^{2x}-1)/(e^{2x}+1) via exp2 + rcp. Saturates correctly
// (e->inf => 1, e->0 => -1); ~1 ulp f32, negligible vs f16 recurrence noise.
__device__ __forceinline__ float fast_tanh(float x) {
#if defined(__HIP_DEVICE_COMPILE__) && __has_builtin(__builtin_amdgcn_exp2f)
    float e = __builtin_amdgcn_exp2f(x * 2.885390081777927f);
#else
    float e = __expf(2.0f * x);
#endif
#if defined(__HIP_DEVICE_COMPILE__) && __has_builtin(__builtin_amdgcn_rcpf)
    return 1.0f - 2.0f * __builtin_amdgcn_rcpf(e + 1.0f);
#else
    return 1.0f - 2.0f / (e + 1.0f);
#endif
}

// ---- dtype detection ------------------------------------------------------
__global__ void detect_dtype(const unsigned short* __restrict__ w, int* __restrict__ flag) {
    if (threadIdx.x == 0 && blockIdx.x == 0) {
        int f = 0;
        for (int i = 0; i < 512; ++i) {
            unsigned e = (w[i] >> 7) & 0xFF;
            if (e >= 127) f = 1;
        }
        *flag = f;
    }
}

// ---- prep: weights (bf16|f32) -> f16, bias sums -> f32, zero carries -----
__global__ void prep_w(const void* __restrict__ wih0, const void* __restrict__ whh0,
                       const void* __restrict__ bih0, const void* __restrict__ bhh0,
                       const void* __restrict__ wih1, const void* __restrict__ whh1,
                       const void* __restrict__ bih1, const void* __restrict__ bhh1,
                       _Float16* __restrict__ owih0, _Float16* __restrict__ owhh0,
                       _Float16* __restrict__ owih1, _Float16* __restrict__ owhh1,
                       float* __restrict__ obias0, float* __restrict__ obias1,
                       uint4* __restrict__ carries, const int* __restrict__ flag) {
    const bool f32 = (*flag != 0);
    int i = blockIdx.x * 256 + threadIdx.x;
    auto rd = [&](const void* p, int idx) -> float {
        return f32 ? ((const float*)p)[idx] : bf2f(((const unsigned short*)p)[idx]);
    };
    if (i < H_ * D_) owih0[i] = (_Float16)rd(wih0, i);
    if (i < H_ * H_) {
        owhh0[i] = (_Float16)rd(whh0, i);
        owih1[i] = (_Float16)rd(wih1, i);
        owhh1[i] = (_Float16)rd(whh1, i);
    }
    if (i < H_) {
        obias0[i] = rd(bih0, i) + rd(bhh0, i);
        obias1[i] = rd(bih1, i) + rd(bhh1, i);
    }
    if (i < (2 * B_ * H_) / 8) carries[i] = uint4{0, 0, 0, 0};
}

// ---- chunk projection: xw[m][j] = A_row(m) . W[j] + bias[j] --------------
template <int K, bool SRCX>
__global__ __launch_bounds__(256, 1) void proj_chunk(const void* __restrict__ A,
                                                     const _Float16* __restrict__ W,
                                                     const float* __restrict__ bias,
                                                     _Float16* __restrict__ outx,
                                                     const int* __restrict__ flag,
                                                     int t0, int Tc) {
    constexpr int KW = K / 8;  // uint4 (8 f16) per row
    const int j = threadIdx.x;
    const long m0 = (long)blockIdx.x * 16;
    const bool f32 = SRCX && (*flag != 0);

    long arow0;
    if (SRCX) {
        long b = m0 / Tc;
        long tc0 = m0 - b * Tc;
        arow0 = (b * T_ + t0 + tc0) * (long)K;
    } else {
        arow0 = m0 * (long)K;
    }

    uint4 w[KW];
    const uint4* wp = (const uint4*)(W + (long)j * K);
#pragma unroll
    for (int i = 0; i < KW; ++i) w[i] = wp[i];

    __shared__ uint4 xt[16 * KW];
    for (int i = threadIdx.x; i < 16 * KW; i += 256) {
        int r = i / KW, c = i % KW;
        long off = arow0 + (long)r * K + (long)c * 8;  // element offset
        if (SRCX) {
            if (f32) {
                const float* s = (const float*)A + off;
                union { _Float16 h[8]; uint4 u; } r8;
#pragma unroll
                for (int q = 0; q < 8; ++q) r8.h[q] = (_Float16)s[q];
                xt[i] = r8.u;
            } else {
                xt[i] = cvt8_bf16_to_f16(*(const uint4*)((const unsigned short*)A + off));
            }
        } else {
            xt[i] = *(const uint4*)((const _Float16*)A + off);
        }
    }
    __syncthreads();

    const float bb = bias[j];
#pragma unroll 1
    for (int r = 0; r < 16; ++r) {
        const uint4* xr = xt + r * KW;
        float a0 = 0.f, a1 = 0.f, a2 = 0.f, a3 = 0.f;
#pragma unroll
        for (int i = 0; i < KW; ++i) {
            uint4 h = xr[i];   // wave-uniform LDS broadcast
            uint4 ww = w[i];
            a0 = dot2(ww.x, h.x, a0);
            a1 = dot2(ww.y, h.y, a1);
            a2 = dot2(ww.z, h.z, a2);
            a3 = dot2(ww.w, h.w, a3);
        }
        outx[(m0 + r) * H_ + j] = (_Float16)(((a0 + a1) + (a2 + a3)) + bb);
    }
}

// ---- fused two-layer scan: 1 WG/batch, 768 threads = 3 groups ------------
// Pipeline (iteration it, parity p = it&1; buffers read [p], written [p^1]):
//   G0  (it<Tc)        : h0[t0+it]    from h0buf[p](=h0[t0+it-1]) + xw0
//   G1a (1<=it<=Tc)    : xw1[t0+it-1] from h0buf[p]
//   G1b (it>=2)        : h1[t0+it-2]  from h1buf[p](=h1[t0+it-3]) + xw1buf[p]
// Out store delayed one iteration so the global write retires under the
// following step instead of stalling the pre-barrier vmcnt(0) drain.
__global__ __launch_bounds__(768, 1) void fused_scan(
    const _Float16* __restrict__ xw0,   // [B][Tc][H]
    const _Float16* __restrict__ Whh0,
    const _Float16* __restrict__ Wih1,
    const _Float16* __restrict__ Whh1,
    const float* __restrict__ bias1,
    _Float16* __restrict__ carry0,      // [B][H] h0[t0-1]
    _Float16* __restrict__ carry1,      // [B][H] h1[t0-1]
    _Float16* __restrict__ tmp,         // [B][Tc][H] h1 chunk, f16
    int Tc)
{
    const int j = threadIdx.x & (H_ - 1);
    const int g = threadIdx.x >> 8;     // 0: layer0, 1: W_ih1 proj, 2: layer1
    const int b = blockIdx.x;

    const _Float16* Wbase = (g == 0) ? Whh0 : ((g == 1) ? Wih1 : Whh1);
    uint4 w[32];                        // 256 f16 = one weight row
    const uint4* wp = (const uint4*)(Wbase + (long)j * H_);
#pragma unroll
    for (int i = 0; i < 32; ++i) w[i] = wp[i];
    // Pin the row in arch VGPRs: the opaque asm makes the loaded values the
    // source of truth, so the compiler can neither rematerialize the loads
    // inside the t-loop nor demote the array (scan_chunk showed VGPR_Count=80,
    // i.e. the 128-reg array was NOT register-resident).
#pragma unroll
    for (int i = 0; i < 32; ++i)
        asm volatile("" : "+v"(w[i].x), "+v"(w[i].y), "+v"(w[i].z), "+v"(w[i].w));

    __shared__ uint4 h0buf[2][32];      // h0 packed f16, double-buffered
    __shared__ uint4 h1buf[2][32];      // h1 packed f16
    __shared__ float xw1buf[2][H_];     // layer-1 pre-activation (f32)

    if (g == 0) ((_Float16*)&h0buf[0][0])[j] = carry0[b * H_ + j];
    if (g == 2) ((_Float16*)&h1buf[0][0])[j] = carry1[b * H_ + j];
    __syncthreads();

    const _Float16* xp = xw0 + ((long)b * Tc) * H_ + j;
    _Float16* tp = tmp + ((long)b * Tc) * H_ + j;
    const float bb = (g == 1) ? bias1[j] : 0.f;

    float xv = (g == 0) ? (float)xp[0] : 0.f;   // xw0 prefetch (lag 1)
    _Float16 h0last = (_Float16)0.f;
    _Float16 pend   = (_Float16)0.f;            // h1 awaiting store (lag 1)

#pragma unroll 1
    for (int it = 0; it < Tc + 2; ++it) {
        const int p = it & 1;
        if (g == 0) {
            if (it < Tc) {
                float xn = 0.f;
                if (it + 1 < Tc) xn = (float)xp[(long)(it + 1) * H_];  // issue early
                const uint4* hb = h0buf[p];
                float a0 = 0.f, a1 = 0.f, a2 = 0.f, a3 = 0.f;
#pragma unroll
                for (int i = 0; i < 32; ++i) {
                    uint4 h = hb[i];  // wave-uniform LDS broadcast
                    uint4 ww = w[i];
                    a0 = dot2(ww.x, h.x, a0);
                    a1 = dot2(ww.y, h.y, a1);
                    a2 = dot2(ww.z, h.z, a2);
                    a3 = dot2(ww.w, h.w, a3);
                }
                float hv = fast_tanh(((a0 + a1) + (a2 + a3)) + xv);
                h0last = (_Float16)hv;
                ((_Float16*)&h0buf[p ^ 1][0])[j] = h0last;
                xv = xn;
            }
        } else if (g == 1) {
            if (it >= 1 && it <= Tc) {
                const uint4* hb = h0buf[p];
                float a0 = 0.f, a1 = 0.f, a2 = 0.f, a3 = 0.f;
#pragma unroll
                for (int i = 0; i < 32; ++i) {
                    uint4 h = hb[i];
                    uint4 ww = w[i];
                    a0 = dot2(ww.x, h.x, a0);
                    a1 = dot2(ww.y, h.y, a1);
                    a2 = dot2(ww.z, h.z, a2);
                    a3 = dot2(ww.w, h.w, a3);
                }
                xw1buf[p ^ 1][j] = ((a0 + a1) + (a2 + a3)) + bb;
            }
        } else {
            if (it >= 3) tp[(long)(it - 3) * H_] = pend;  // store early in step
            if (it >= 2) {
                const uint4* hb = h1buf[p];
                float a0 = 0.f, a1 = 0.f, a2 = 0.f, a3 = 0.f;
#pragma unroll
                for (int i = 0; i < 32; ++i) {
                    uint4 h = hb[i];
                    uint4 ww = w[i];
                    a0 = dot2(ww.x, h.x, a0);
                    a1 = dot2(ww.y, h.y, a1);
                    a2 = dot2(ww.z, h.z, a2);
                    a3 = dot2(ww.w, h.w, a3);
                }
                float hv = fast_tanh(((a0 + a1) + (a2 + a3)) + xw1buf[p][j]);
                pend = (_Float16)hv;
                ((_Float16*)&h1buf[p ^ 1][0])[j] = pend;
            }
        }
        __syncthreads();
    }

    if (g == 0) carry0[b * H_ + j] = h0last;           // h0[t0+Tc-1]
    if (g == 2) {
        tp[(long)(Tc - 1) * H_] = pend;                // final h1 of chunk
        carry1[b * H_ + j] = pend;                     // h1[t0+Tc-1]
    }
}

// ---- transpose: tmp [b][tc][j] f16 -> out [b][j][t0+tc] (bf16|f32) -------
__global__ __launch_bounds__(256, 1) void transpose_out(
    const _Float16* __restrict__ tmp, void* __restrict__ out,
    const int* __restrict__ flag, int t0, int Tc)
{
    const int nTc = (Tc + 63) >> 6;
    int bid = blockIdx.x;
    const int jblk = bid & 3; bid >>= 2;           // H_/64 == 4
    const int tcblk = bid % nTc;
    const int b = bid / nTc;
    const bool f32o = (*flag != 0);
    const int tid = threadIdx.x;

    __shared__ float tile[64][65];                 // 65: conflict-free both axes
#pragma unroll
    for (int k = 0; k < 16; ++k) {
        int idx = k * 256 + tid;
        int r = idx >> 6, c = idx & 63;
        int tc = tcblk * 64 + r;
        tile[r][c] = (tc < Tc)
            ? (float)tmp[((long)b * Tc + tc) * H_ + jblk * 64 + c] : 0.f;
    }
    __syncthreads();
#pragma unroll
    for (int k = 0; k < 16; ++k) {
        int idx = k * 256 + tid;
        int jr = idx >> 6, tc = idx & 63;
        if (tcblk * 64 + tc < Tc) {
            float v = tile[tc][jr];
            long o = ((long)b * H_ + jblk * 64 + jr) * (long)T_ + t0 + tcblk * 64 + tc;
            if (f32o) ((float*)out)[o] = v;
            else      ((__hip_bfloat16*)out)[o] = __float2bfloat16(v);
        }
    }
}

// ---------------------------------------------------------------------------
extern "C" void kernel_launch(void* const* d_in, const int* in_sizes, int n_in,
                              void* d_out, int out_size, void* d_ws, size_t ws_size,
                              hipStream_t stream) {
    const void* x    = d_in[0];
    const void* wih0 = d_in[1];
    const void* whh0 = d_in[2];
    const void* bih0 = d_in[3];
    const void* bhh0 = d_in[4];
    const void* wih1 = d_in[5];
    const void* whh1 = d_in[6];
    const void* bih1 = d_in[7];
    const void* bhh1 = d_in[8];
    (void)in_sizes; (void)n_in; (void)out_size;

    char* ws = (char*)d_ws;
    size_t off = 0;
    auto alloc = [&](size_t bytes) -> void* {
        void* p = ws + off;
        off += (bytes + 255) & ~(size_t)255;
        return p;
    };

    int*      flag    = (int*)alloc(256);
    _Float16* wih0_16 = (_Float16*)alloc((size_t)H_ * D_ * 2);
    _Float16* whh0_16 = (_Float16*)alloc((size_t)H_ * H_ * 2);
    _Float16* wih1_16 = (_Float16*)alloc((size_t)H_ * H_ * 2);
    _Float16* whh1_16 = (_Float16*)alloc((size_t)H_ * H_ * 2);
    float*    bias0   = (float*)alloc(H_ * 4);
    float*    bias1   = (float*)alloc(H_ * 4);
    _Float16* carry0  = (_Float16*)alloc((size_t)B_ * H_ * 2);
    _Float16* carry1  = (_Float16*)alloc((size_t)B_ * H_ * 2);
    size_t fixed = off;

    // largest chunk Tc (<=256) whose two chunk buffers (xw0 + h1 tmp) fit
    int Tc = 256;
    while (Tc > 16 && fixed + 2 * ((size_t)B_ * Tc * H_ * 2 + 256) > ws_size) Tc >>= 1;
    _Float16* xwc  = (_Float16*)alloc((size_t)B_ * Tc * H_ * 2);
    _Float16* tmpc = (_Float16*)alloc((size_t)B_ * Tc * H_ * 2);

    detect_dtype<<<1, 64, 0, stream>>>((const unsigned short*)whh0, flag);
    prep_w<<<(H_ * H_ + 255) / 256, 256, 0, stream>>>(
        wih0, whh0, bih0, bhh0, wih1, whh1, bih1, bhh1,
        wih0_16, whh0_16, wih1_16, whh1_16, bias0, bias1, (uint4*)carry0, flag);

    const int nproj = (B_ * Tc) / 16;
    const int nTc   = (Tc + 63) / 64;
    for (int t0 = 0; t0 < T_; t0 += Tc) {
        proj_chunk<D_, true><<<nproj, 256, 0, stream>>>(x, wih0_16, bias0, xwc, flag, t0, Tc);
        fused_scan<<<B_, 768, 0, stream>>>(xwc, whh0_16, wih1_16, whh1_16, bias1,
                                           carry0, carry1, tmpc, Tc);
        transpose_out<<<B_ * nTc * (H_ / 64), 256, 0, stream>>>(tmpc, d_out, flag, t0, Tc);
    }
}